// Round 12
// baseline (149.367 us; speedup 1.0000x reference)
//
#include <hip/hip_runtime.h>
#include <math.h>

#define N_NODES 50000
#define N_EDGES 800000
#define N_GRAPHS 512
#define D 64
#define D_CLS 128
#define BNODES 128                       // dst nodes per bucket
#define NBUK 391                         // cdiv(N_NODES, BNODES)
#define BSTRIDE 4096                     // padded slots per bucket (mean 2046, 45 sigma)
#define PART_TILE 4096                   // edges per partition block (256 thr x 16)

typedef _Float16 h4 __attribute__((ext_vector_type(4)));
typedef float    f4 __attribute__((ext_vector_type(4)));

static inline int cdiv(int a, int b) { return (a + b - 1) / b; }

// ---------- bucket tails init (padded layout: bucket b owns [b*BSTRIDE, ...)) --

__global__ void k_binit(int* __restrict__ btail) {
    int b = blockIdx.x * blockDim.x + threadIdx.x;
    if (b < NBUK) btail[b] = b * BSTRIDE;
}

// ---------- partition edges into buckets (LDS histogram, dense writes) --------

__global__ __launch_bounds__(256) void k_part(
        const int* __restrict__ src, const int* __restrict__ dst,
        int* __restrict__ btail, int* __restrict__ ebuf) {
    __shared__ int lcnt[NBUK];
    __shared__ int lbase[NBUK];
    int t = threadIdx.x;
    for (int i = t; i < NBUK; i += 256) lcnt[i] = 0;
    __syncthreads();

    int e0 = blockIdx.x * PART_TILE + t;
    int ent[16];
    int br[16];
    #pragma unroll
    for (int k = 0; k < 16; k++) {
        int e = e0 + k * 256;
        if (e < N_EDGES) {
            int d = dst[e];
            int b = d / BNODES;
            int r = atomicAdd(&lcnt[b], 1);
            ent[k] = src[e] | ((d & (BNODES - 1)) << 16);  // src(16b)|dlocal(7b)
            br[k] = (b << 16) | r;                          // r < 4096
        } else {
            br[k] = -1;
        }
    }
    __syncthreads();
    for (int i = t; i < NBUK; i += 256) {
        int c = lcnt[i];
        lbase[i] = c ? atomicAdd(&btail[i], c) : 0;
    }
    __syncthreads();
    #pragma unroll
    for (int k = 0; k < 16; k++) {
        if (br[k] >= 0) {
            int b = br[k] >> 16, r = br[k] & 0xFFFF;
            ebuf[lbase[b] + r] = ent[k];
        }
    }
}

// ---------- per-bucket CSR build (two-pass, global reads; proven in R10) ------
// One block per bucket; bucket slice contiguous and L2-hot on pass 2.
// Emits per-node rng = (start, end) as int2, dis, node-sorted col.

__global__ __launch_bounds__(256) void k_build(
        const int* __restrict__ ebuf, const int* __restrict__ btail,
        int2* __restrict__ rng, float* __restrict__ dis,
        int* __restrict__ col) {
    __shared__ int hist[BNODES];
    __shared__ int base[BNODES];
    __shared__ int cur[BNODES];
    int t = threadIdx.x;
    int b = blockIdx.x;
    int s = b * BSTRIDE;
    int e = btail[b];

    if (t < BNODES) { hist[t] = 0; cur[t] = 0; }
    __syncthreads();

    // pass 1: per-node counts
    for (int i = s + t; i < e; i += 256)
        atomicAdd(&hist[(ebuf[i] >> 16) & (BNODES - 1)], 1);
    __syncthreads();

    // inclusive scan of hist into base
    if (t < BNODES) base[t] = hist[t];
    __syncthreads();
    for (int off = 1; off < BNODES; off <<= 1) {
        int x = 0;
        if (t < BNODES && t >= off) x = base[t - off];
        __syncthreads();
        if (t < BNODES) base[t] += x;
        __syncthreads();
    }
    if (t < BNODES) {
        int ex = base[t] - hist[t];
        base[t] = ex;
        int n = b * BNODES + t;
        if (n < N_NODES) {
            rng[n] = make_int2(s + ex, s + ex + hist[t]);
            dis[n] = rsqrtf((float)hist[t] + 1.0f);
        }
    }
    __syncthreads();

    // pass 2: place
    for (int i = s + t; i < e; i += 256) {
        int v = ebuf[i];
        int d = (v >> 16) & (BNODES - 1);
        int pos = atomicAdd(&cur[d], 1);
        col[s + base[d] + pos] = v & 0xFFFF;
    }
}

// ---------- GEMM: G16 = fp16( dis ⊙ (X @ W) ), f32 accumulate ----------
// HALF_IN selects fp16 H input (layers 1-2) vs f32 x input (layer 0).

#define XS_STRIDE 68   // 64 + 4 pad, keeps 16B alignment for float4 LDS ops

template<bool HALF_IN>
__global__ __launch_bounds__(256) void k_gemm_scale(
        const void* __restrict__ Xv, const float* __restrict__ W,
        const float* __restrict__ dis, _Float16* __restrict__ G16) {
    __shared__ float Xs[64 * XS_STRIDE];
    __shared__ float Ws[64 * 64];
    int n0 = blockIdx.x * 64;
    int t = threadIdx.x;

    {
        int base = t * 16;
        const float4* wsrc = (const float4*)(W + base);
        float4* wdst = (float4*)(Ws + base);
        wdst[0] = wsrc[0]; wdst[1] = wsrc[1]; wdst[2] = wsrc[2]; wdst[3] = wsrc[3];
    }
    {
        int row = t >> 2;
        int c0 = (t & 3) * 16;
        int grow = n0 + row;
        float* xd = Xs + row * XS_STRIDE + c0;
        if (grow < N_NODES) {
            if (HALF_IN) {
                const h4* xp = (const h4*)((const _Float16*)Xv + (size_t)grow * D + c0);
                #pragma unroll
                for (int j = 0; j < 4; j++)
                    *(f4*)(xd + j * 4) = __builtin_convertvector(xp[j], f4);
            } else {
                const float4* xp = (const float4*)((const float*)Xv + (size_t)grow * D + c0);
                float4* xd4 = (float4*)xd;
                xd4[0] = xp[0]; xd4[1] = xp[1]; xd4[2] = xp[2]; xd4[3] = xp[3];
            }
        } else {
            float4 z = {0.f, 0.f, 0.f, 0.f};
            float4* xd4 = (float4*)xd;
            xd4[0] = z; xd4[1] = z; xd4[2] = z; xd4[3] = z;
        }
    }
    __syncthreads();

    int tc = t & 15, tr = t >> 4;
    int r0 = tr * 4, c0 = tc * 4;
    float acc[4][4] = {};
    #pragma unroll 4
    for (int k = 0; k < 64; k++) {
        float4 wv = *(const float4*)&Ws[k * 64 + c0];
        #pragma unroll
        for (int i = 0; i < 4; i++) {
            float xv = Xs[(r0 + i) * XS_STRIDE + k];
            acc[i][0] = fmaf(xv, wv.x, acc[i][0]);
            acc[i][1] = fmaf(xv, wv.y, acc[i][1]);
            acc[i][2] = fmaf(xv, wv.z, acc[i][2]);
            acc[i][3] = fmaf(xv, wv.w, acc[i][3]);
        }
    }
    #pragma unroll
    for (int i = 0; i < 4; i++) {
        int grow = n0 + r0 + i;
        if (grow < N_NODES) {
            float dsc = dis[grow];
            h4 o;
            o.x = (_Float16)(acc[i][0] * dsc);
            o.y = (_Float16)(acc[i][1] * dsc);
            o.z = (_Float16)(acc[i][2] * dsc);
            o.w = (_Float16)(acc[i][3] * dsc);
            *(h4*)&G16[(size_t)grow * D + c0] = o;
        }
    }
}

// ---------- aggregation: fp16 gather table, f32 accumulate, fp16 H out --------
// 16-lane group per node (lane owns 4 features = 8B of the 128B row).
// 8-deep predicated edge walk -> 8 gathers in flight per lane.
// Bound: 2 cache-line requests per edge (1.6M lines/dispatch) = L2 service floor.

__global__ __launch_bounds__(256) void k_agg(
        const _Float16* __restrict__ G16, const int2* __restrict__ rng,
        const int* __restrict__ col, const float* __restrict__ dis,
        const float* __restrict__ bias, _Float16* __restrict__ Hout) {
    int t = threadIdx.x;
    int grp = t >> 4;                 // 16 node-groups per block
    int fl4 = (t & 15) * 4;           // feature offset (4 feats per lane)
    int n = blockIdx.x * 16 + grp;    // grid = 3125 -> n < 50000 always

    int2 r = rng[n];
    int s = r.x, e = r.y;
    f4 acc = __builtin_convertvector(*(const h4*)(G16 + (size_t)n * D + fl4), f4);

    for (int i = s; i < e; i += 8) {
        int i1 = i + 1, i2 = i + 2, i3 = i + 3;
        int i4 = i + 4, i5 = i + 5, i6 = i + 6, i7 = i + 7;
        int c0 = col[i];
        int c1 = col[i1 < e ? i1 : i];
        int c2 = col[i2 < e ? i2 : i];
        int c3 = col[i3 < e ? i3 : i];
        int c4 = col[i4 < e ? i4 : i];
        int c5 = col[i5 < e ? i5 : i];
        int c6 = col[i6 < e ? i6 : i];
        int c7 = col[i7 < e ? i7 : i];
        float f1 = (i1 < e) ? 1.f : 0.f;
        float f2 = (i2 < e) ? 1.f : 0.f;
        float f3 = (i3 < e) ? 1.f : 0.f;
        float f4_ = (i4 < e) ? 1.f : 0.f;
        float f5 = (i5 < e) ? 1.f : 0.f;
        float f6 = (i6 < e) ? 1.f : 0.f;
        float f7 = (i7 < e) ? 1.f : 0.f;
        f4 g0 = __builtin_convertvector(*(const h4*)(G16 + (size_t)c0 * D + fl4), f4);
        f4 g1 = __builtin_convertvector(*(const h4*)(G16 + (size_t)c1 * D + fl4), f4);
        f4 g2 = __builtin_convertvector(*(const h4*)(G16 + (size_t)c2 * D + fl4), f4);
        f4 g3 = __builtin_convertvector(*(const h4*)(G16 + (size_t)c3 * D + fl4), f4);
        f4 g4 = __builtin_convertvector(*(const h4*)(G16 + (size_t)c4 * D + fl4), f4);
        f4 g5 = __builtin_convertvector(*(const h4*)(G16 + (size_t)c5 * D + fl4), f4);
        f4 g6 = __builtin_convertvector(*(const h4*)(G16 + (size_t)c6 * D + fl4), f4);
        f4 g7 = __builtin_convertvector(*(const h4*)(G16 + (size_t)c7 * D + fl4), f4);
        acc += g0;
        acc += f1 * g1;
        acc += f2 * g2;
        acc += f3 * g3;
        acc += f4_ * g4;
        acc += f5 * g5;
        acc += f6 * g6;
        acc += f7 * g7;
    }

    float dsc = dis[n];
    f4 bv = *(const f4*)(bias + fl4);
    f4 o = dsc * acc + bv;
    h4 oh;
    oh.x = (_Float16)o.x; oh.y = (_Float16)o.y;
    oh.z = (_Float16)o.z; oh.w = (_Float16)o.w;
    *(h4*)(Hout + (size_t)n * D + fl4) = oh;
}

// ---------- fused pooling + classifier MLP (one block per graph) ----------

__device__ __forceinline__ int lower_bound_batch(const int* batch, int g) {
    int lo = 0, hi = N_NODES;
    while (lo < hi) {
        int mid = (lo + hi) >> 1;
        if (batch[mid] < g) lo = mid + 1; else hi = mid;
    }
    return lo;
}

__global__ __launch_bounds__(128) void k_poolmlp(
        const _Float16* __restrict__ H16, const int* __restrict__ batch,
        const float* __restrict__ w1, const float* __restrict__ b1,
        const float* __restrict__ w2, const float* __restrict__ b2,
        const float* __restrict__ fcw, const float* __restrict__ fcb,
        float* __restrict__ out) {
    __shared__ float ps[64];
    __shared__ float red[128];
    int g = blockIdx.x, t = threadIdx.x;
    int s = lower_bound_batch(batch, g);
    int e = lower_bound_batch(batch, g + 1);

    // pool: 2 row-slots x 64 feats
    int f = t & 63, slot = t >> 6;
    float acc = 0.f;
    for (int r = s + slot; r < e; r += 2)
        acc += (float)H16[(size_t)r * D + f];
    red[t] = acc;
    __syncthreads();
    if (t < 64) {
        int cnt = e - s;
        ps[t] = (red[t] + red[t + 64]) / (float)(cnt > 0 ? cnt : 1);
    }
    __syncthreads();

    // MLP: 128 threads own one D_CLS column each
    float a = b1[t];
    #pragma unroll
    for (int k = 0; k < 64; k++) a = fmaf(ps[k], w1[k * D_CLS + t], a);
    red[t] = a * w2[t];
    __syncthreads();
    for (int s2 = 64; s2 > 0; s2 >>= 1) {
        if (t < s2) red[t] += red[t + s2];
        __syncthreads();
    }
    if (t == 0) {
        float o = red[0] + b2[0];
        o = fmaf(o, fcw[0], fcb[0]);
        out[g] = (o >= 0.f) ? o : 0.01f * o;
    }
}

// ---------- launch ----------

extern "C" void kernel_launch(void* const* d_in, const int* in_sizes, int n_in,
                              void* d_out, int out_size, void* d_ws, size_t ws_size,
                              hipStream_t stream) {
    const float* x   = (const float*)d_in[0];
    const float* W0  = (const float*)d_in[1];
    const float* b0  = (const float*)d_in[2];
    const float* W1  = (const float*)d_in[3];
    const float* b1  = (const float*)d_in[4];
    const float* W2  = (const float*)d_in[5];
    const float* b2  = (const float*)d_in[6];
    const float* l1w = (const float*)d_in[7];
    const float* l1b = (const float*)d_in[8];
    const float* l2w = (const float*)d_in[9];
    const float* l2b = (const float*)d_in[10];
    const float* fcw = (const float*)d_in[11];
    const float* fcb = (const float*)d_in[12];
    const int* eidx  = (const int*)d_in[13];
    const int* batch = (const int*)d_in[14];
    const int* src = eidx;
    const int* dst = eidx + N_EDGES;

    char* ws = (char*)d_ws;
    size_t off = 0;
    auto alloc = [&](size_t bytes) -> void* {
        off = (off + 255) & ~(size_t)255;
        void* p = ws + off;
        off += bytes;
        return p;
    };

    int2*  rng    = (int2*) alloc(N_NODES * sizeof(int2));
    int*   btail  = (int*)  alloc(NBUK * sizeof(int));
    int*   ebuf   = (int*)  alloc((size_t)NBUK * BSTRIDE * sizeof(int));
    int*   col    = (int*)  alloc((size_t)NBUK * BSTRIDE * sizeof(int));
    float* dis    = (float*)alloc(N_NODES * sizeof(float));
    _Float16* G16 = (_Float16*)alloc((size_t)N_NODES * D * sizeof(_Float16));
    _Float16* H1  = (_Float16*)alloc((size_t)N_NODES * D * sizeof(_Float16));
    _Float16* H2  = (_Float16*)alloc((size_t)N_NODES * D * sizeof(_Float16));

    const int nbPart = cdiv(N_EDGES, PART_TILE);   // 196

    k_binit<<<cdiv(NBUK, 256), 256, 0, stream>>>(btail);
    k_part<<<nbPart, 256, 0, stream>>>(src, dst, btail, ebuf);
    k_build<<<NBUK, 256, 0, stream>>>(ebuf, btail, rng, dis, col);

    const int nbGemm = cdiv(N_NODES, 64);    // 782
    const int nbAgg  = cdiv(N_NODES, 16);    // 3125

    // layer 0: x (f32) -> H1
    k_gemm_scale<false><<<nbGemm, 256, 0, stream>>>(x, W0, dis, G16);
    k_agg<<<nbAgg, 256, 0, stream>>>(G16, rng, col, dis, b0, H1);
    // layer 1: H1 -> H2
    k_gemm_scale<true><<<nbGemm, 256, 0, stream>>>(H1, W1, dis, G16);
    k_agg<<<nbAgg, 256, 0, stream>>>(G16, rng, col, dis, b1, H2);
    // layer 2: H2 -> H1
    k_gemm_scale<true><<<nbGemm, 256, 0, stream>>>(H2, W2, dis, G16);
    k_agg<<<nbAgg, 256, 0, stream>>>(G16, rng, col, dis, b2, H1);

    k_poolmlp<<<N_GRAPHS, 128, 0, stream>>>(H1, batch, l1w, l1b, l2w, l2b,
                                            fcw, fcb, (float*)d_out);
}

// Round 13
// 138.180 us; speedup vs baseline: 1.0810x; 1.0810x over previous
//
#include <hip/hip_runtime.h>
#include <math.h>

#define N_NODES 50000
#define N_EDGES 800000
#define N_GRAPHS 512
#define D 64
#define D_CLS 128
#define BNODES 128                       // dst nodes per bucket
#define NBUK 391                         // cdiv(N_NODES, BNODES)
#define BSTRIDE 4096                     // padded slots per bucket (mean 2046, 45 sigma)
#define PART_TILE 4096                   // edges per partition block (256 thr x 16)

typedef _Float16 h4 __attribute__((ext_vector_type(4)));
typedef float    f4 __attribute__((ext_vector_type(4)));

static inline int cdiv(int a, int b) { return (a + b - 1) / b; }

// ---------- bucket tails init (padded layout: bucket b owns [b*BSTRIDE, ...)) --

__global__ void k_binit(int* __restrict__ btail) {
    int b = blockIdx.x * blockDim.x + threadIdx.x;
    if (b < NBUK) btail[b] = b * BSTRIDE;
}

// ---------- partition edges into buckets (LDS histogram, dense writes) --------

__global__ __launch_bounds__(256) void k_part(
        const int* __restrict__ src, const int* __restrict__ dst,
        int* __restrict__ btail, int* __restrict__ ebuf) {
    __shared__ int lcnt[NBUK];
    __shared__ int lbase[NBUK];
    int t = threadIdx.x;
    for (int i = t; i < NBUK; i += 256) lcnt[i] = 0;
    __syncthreads();

    int e0 = blockIdx.x * PART_TILE + t;
    int ent[16];
    int br[16];
    #pragma unroll
    for (int k = 0; k < 16; k++) {
        int e = e0 + k * 256;
        if (e < N_EDGES) {
            int d = dst[e];
            int b = d / BNODES;
            int r = atomicAdd(&lcnt[b], 1);
            ent[k] = src[e] | ((d & (BNODES - 1)) << 16);  // src(16b)|dlocal(7b)
            br[k] = (b << 16) | r;                          // r < 4096
        } else {
            br[k] = -1;
        }
    }
    __syncthreads();
    for (int i = t; i < NBUK; i += 256) {
        int c = lcnt[i];
        lbase[i] = c ? atomicAdd(&btail[i], c) : 0;
    }
    __syncthreads();
    #pragma unroll
    for (int k = 0; k < 16; k++) {
        if (br[k] >= 0) {
            int b = br[k] >> 16, r = br[k] & 0xFFFF;
            ebuf[lbase[b] + r] = ent[k];
        }
    }
}

// ---------- per-bucket CSR build (two-pass, global reads) ----------

__global__ __launch_bounds__(256) void k_build(
        const int* __restrict__ ebuf, const int* __restrict__ btail,
        int2* __restrict__ rng, float* __restrict__ dis,
        int* __restrict__ col) {
    __shared__ int hist[BNODES];
    __shared__ int base[BNODES];
    __shared__ int cur[BNODES];
    int t = threadIdx.x;
    int b = blockIdx.x;
    int s = b * BSTRIDE;
    int e = btail[b];

    if (t < BNODES) { hist[t] = 0; cur[t] = 0; }
    __syncthreads();

    for (int i = s + t; i < e; i += 256)
        atomicAdd(&hist[(ebuf[i] >> 16) & (BNODES - 1)], 1);
    __syncthreads();

    if (t < BNODES) base[t] = hist[t];
    __syncthreads();
    for (int off = 1; off < BNODES; off <<= 1) {
        int x = 0;
        if (t < BNODES && t >= off) x = base[t - off];
        __syncthreads();
        if (t < BNODES) base[t] += x;
        __syncthreads();
    }
    if (t < BNODES) {
        int ex = base[t] - hist[t];
        base[t] = ex;
        int n = b * BNODES + t;
        if (n < N_NODES) {
            rng[n] = make_int2(s + ex, s + ex + hist[t]);
            dis[n] = rsqrtf((float)hist[t] + 1.0f);
        }
    }
    __syncthreads();

    for (int i = s + t; i < e; i += 256) {
        int v = ebuf[i];
        int d = (v >> 16) & (BNODES - 1);
        int pos = atomicAdd(&cur[d], 1);
        col[s + base[d] + pos] = v & 0xFFFF;
    }
}

// ---------- layer-0 GEMM: G16 = fp16( dis ⊙ (x @ W0) ), f32 accumulate --------

#define XS_STRIDE 68   // 64 + 4 pad, keeps 16B alignment for float4 LDS ops

__global__ __launch_bounds__(256) void k_gemm_scale(
        const float* __restrict__ X, const float* __restrict__ W,
        const float* __restrict__ dis, _Float16* __restrict__ G16) {
    __shared__ float Xs[64 * XS_STRIDE];
    __shared__ float Ws[64 * 64];
    int n0 = blockIdx.x * 64;
    int t = threadIdx.x;

    {
        int base = t * 16;
        const float4* wsrc = (const float4*)(W + base);
        float4* wdst = (float4*)(Ws + base);
        wdst[0] = wsrc[0]; wdst[1] = wsrc[1]; wdst[2] = wsrc[2]; wdst[3] = wsrc[3];
    }
    {
        int row = t >> 2;
        int c0 = (t & 3) * 16;
        int grow = n0 + row;
        float4* xd = (float4*)(Xs + row * XS_STRIDE + c0);
        if (grow < N_NODES) {
            const float4* xp = (const float4*)(X + (size_t)grow * D + c0);
            xd[0] = xp[0]; xd[1] = xp[1]; xd[2] = xp[2]; xd[3] = xp[3];
        } else {
            float4 z = {0.f, 0.f, 0.f, 0.f};
            xd[0] = z; xd[1] = z; xd[2] = z; xd[3] = z;
        }
    }
    __syncthreads();

    int tc = t & 15, tr = t >> 4;
    int r0 = tr * 4, c0 = tc * 4;
    float acc[4][4] = {};
    #pragma unroll 4
    for (int k = 0; k < 64; k++) {
        float4 wv = *(const float4*)&Ws[k * 64 + c0];
        #pragma unroll
        for (int i = 0; i < 4; i++) {
            float xv = Xs[(r0 + i) * XS_STRIDE + k];
            acc[i][0] = fmaf(xv, wv.x, acc[i][0]);
            acc[i][1] = fmaf(xv, wv.y, acc[i][1]);
            acc[i][2] = fmaf(xv, wv.z, acc[i][2]);
            acc[i][3] = fmaf(xv, wv.w, acc[i][3]);
        }
    }
    #pragma unroll
    for (int i = 0; i < 4; i++) {
        int grow = n0 + r0 + i;
        if (grow < N_NODES) {
            float dsc = dis[grow];
            h4 o;
            o.x = (_Float16)(acc[i][0] * dsc);
            o.y = (_Float16)(acc[i][1] * dsc);
            o.z = (_Float16)(acc[i][2] * dsc);
            o.w = (_Float16)(acc[i][3] * dsc);
            *(h4*)&G16[(size_t)grow * D + c0] = o;
        }
    }
}

// ---------- fused aggregation (+ next-layer GEMM in epilogue) ----------
// 16-lane group per node; 8-deep predicated gather; the group holds the full
// f32 H row (4 feats/lane). If !FINAL: broadcast h via shfl(width 16), multiply
// by LDS-staged W_next, write G_next = fp16(dis * (h @ W)). If FINAL: write
// H = fp16(h). VALU of the fused GEMM hides under gather latency.

template<bool FINAL>
__global__ __launch_bounds__(256) void k_agg_fused(
        const _Float16* __restrict__ G16, const int2* __restrict__ rng,
        const int* __restrict__ col, const float* __restrict__ dis,
        const float* __restrict__ bias, const float* __restrict__ Wn,
        _Float16* __restrict__ Gout) {
    __shared__ float Ws[64 * 64];
    int t = threadIdx.x;
    if (!FINAL) {
        int base = t * 16;
        const float4* wsrc = (const float4*)(Wn + base);
        float4* wdst = (float4*)(Ws + base);
        wdst[0] = wsrc[0]; wdst[1] = wsrc[1]; wdst[2] = wsrc[2]; wdst[3] = wsrc[3];
        __syncthreads();
    }

    int grp = t >> 4;                 // 16 node-groups per block
    int fl4 = (t & 15) * 4;           // feature offset (4 feats per lane)
    int n = blockIdx.x * 16 + grp;    // grid = 3125 -> n < 50000 always

    int2 r = rng[n];
    int s = r.x, e = r.y;
    f4 acc = __builtin_convertvector(*(const h4*)(G16 + (size_t)n * D + fl4), f4);

    for (int i = s; i < e; i += 8) {
        int i1 = i + 1, i2 = i + 2, i3 = i + 3;
        int i4 = i + 4, i5 = i + 5, i6 = i + 6, i7 = i + 7;
        int c0 = col[i];
        int c1 = col[i1 < e ? i1 : i];
        int c2 = col[i2 < e ? i2 : i];
        int c3 = col[i3 < e ? i3 : i];
        int c4 = col[i4 < e ? i4 : i];
        int c5 = col[i5 < e ? i5 : i];
        int c6 = col[i6 < e ? i6 : i];
        int c7 = col[i7 < e ? i7 : i];
        float f1 = (i1 < e) ? 1.f : 0.f;
        float f2 = (i2 < e) ? 1.f : 0.f;
        float f3 = (i3 < e) ? 1.f : 0.f;
        float f4_ = (i4 < e) ? 1.f : 0.f;
        float f5 = (i5 < e) ? 1.f : 0.f;
        float f6 = (i6 < e) ? 1.f : 0.f;
        float f7 = (i7 < e) ? 1.f : 0.f;
        f4 g0 = __builtin_convertvector(*(const h4*)(G16 + (size_t)c0 * D + fl4), f4);
        f4 g1 = __builtin_convertvector(*(const h4*)(G16 + (size_t)c1 * D + fl4), f4);
        f4 g2 = __builtin_convertvector(*(const h4*)(G16 + (size_t)c2 * D + fl4), f4);
        f4 g3 = __builtin_convertvector(*(const h4*)(G16 + (size_t)c3 * D + fl4), f4);
        f4 g4 = __builtin_convertvector(*(const h4*)(G16 + (size_t)c4 * D + fl4), f4);
        f4 g5 = __builtin_convertvector(*(const h4*)(G16 + (size_t)c5 * D + fl4), f4);
        f4 g6 = __builtin_convertvector(*(const h4*)(G16 + (size_t)c6 * D + fl4), f4);
        f4 g7 = __builtin_convertvector(*(const h4*)(G16 + (size_t)c7 * D + fl4), f4);
        acc += g0;
        acc += f1 * g1;
        acc += f2 * g2;
        acc += f3 * g3;
        acc += f4_ * g4;
        acc += f5 * g5;
        acc += f6 * g6;
        acc += f7 * g7;
    }

    float dsc = dis[n];
    f4 bv = *(const f4*)(bias + fl4);
    f4 h = dsc * acc + bv;            // full-precision H row (4 feats/lane)

    if (FINAL) {
        h4 oh;
        oh.x = (_Float16)h.x; oh.y = (_Float16)h.y;
        oh.z = (_Float16)h.z; oh.w = (_Float16)h.w;
        *(h4*)(Gout + (size_t)n * D + fl4) = oh;
    } else {
        // G_next[n][c] = dis_n * sum_k h_k * W[k][c], c in [fl4, fl4+4)
        f4 out = {0.f, 0.f, 0.f, 0.f};
        #pragma unroll
        for (int kk = 0; kk < 16; kk++) {
            float h0 = __shfl(h.x, kk, 16);
            float h1 = __shfl(h.y, kk, 16);
            float h2 = __shfl(h.z, kk, 16);
            float h3 = __shfl(h.w, kk, 16);
            f4 w0 = *(const f4*)&Ws[(kk * 4 + 0) * 64 + fl4];
            f4 w1 = *(const f4*)&Ws[(kk * 4 + 1) * 64 + fl4];
            f4 w2 = *(const f4*)&Ws[(kk * 4 + 2) * 64 + fl4];
            f4 w3 = *(const f4*)&Ws[(kk * 4 + 3) * 64 + fl4];
            out += h0 * w0;
            out += h1 * w1;
            out += h2 * w2;
            out += h3 * w3;
        }
        out *= dsc;
        h4 oh;
        oh.x = (_Float16)out.x; oh.y = (_Float16)out.y;
        oh.z = (_Float16)out.z; oh.w = (_Float16)out.w;
        *(h4*)(Gout + (size_t)n * D + fl4) = oh;
    }
}

// ---------- fused pooling + classifier MLP (one block per graph) ----------

__device__ __forceinline__ int lower_bound_batch(const int* batch, int g) {
    int lo = 0, hi = N_NODES;
    while (lo < hi) {
        int mid = (lo + hi) >> 1;
        if (batch[mid] < g) lo = mid + 1; else hi = mid;
    }
    return lo;
}

__global__ __launch_bounds__(128) void k_poolmlp(
        const _Float16* __restrict__ H16, const int* __restrict__ batch,
        const float* __restrict__ w1, const float* __restrict__ b1,
        const float* __restrict__ w2, const float* __restrict__ b2,
        const float* __restrict__ fcw, const float* __restrict__ fcb,
        float* __restrict__ out) {
    __shared__ float ps[64];
    __shared__ float red[128];
    int g = blockIdx.x, t = threadIdx.x;
    int s = lower_bound_batch(batch, g);
    int e = lower_bound_batch(batch, g + 1);

    int f = t & 63, slot = t >> 6;
    float acc = 0.f;
    for (int r = s + slot; r < e; r += 2)
        acc += (float)H16[(size_t)r * D + f];
    red[t] = acc;
    __syncthreads();
    if (t < 64) {
        int cnt = e - s;
        ps[t] = (red[t] + red[t + 64]) / (float)(cnt > 0 ? cnt : 1);
    }
    __syncthreads();

    float a = b1[t];
    #pragma unroll
    for (int k = 0; k < 64; k++) a = fmaf(ps[k], w1[k * D_CLS + t], a);
    red[t] = a * w2[t];
    __syncthreads();
    for (int s2 = 64; s2 > 0; s2 >>= 1) {
        if (t < s2) red[t] += red[t + s2];
        __syncthreads();
    }
    if (t == 0) {
        float o = red[0] + b2[0];
        o = fmaf(o, fcw[0], fcb[0]);
        out[g] = (o >= 0.f) ? o : 0.01f * o;
    }
}

// ---------- launch ----------

extern "C" void kernel_launch(void* const* d_in, const int* in_sizes, int n_in,
                              void* d_out, int out_size, void* d_ws, size_t ws_size,
                              hipStream_t stream) {
    const float* x   = (const float*)d_in[0];
    const float* W0  = (const float*)d_in[1];
    const float* b0  = (const float*)d_in[2];
    const float* W1  = (const float*)d_in[3];
    const float* b1  = (const float*)d_in[4];
    const float* W2  = (const float*)d_in[5];
    const float* b2  = (const float*)d_in[6];
    const float* l1w = (const float*)d_in[7];
    const float* l1b = (const float*)d_in[8];
    const float* l2w = (const float*)d_in[9];
    const float* l2b = (const float*)d_in[10];
    const float* fcw = (const float*)d_in[11];
    const float* fcb = (const float*)d_in[12];
    const int* eidx  = (const int*)d_in[13];
    const int* batch = (const int*)d_in[14];
    const int* src = eidx;
    const int* dst = eidx + N_EDGES;

    char* ws = (char*)d_ws;
    size_t off = 0;
    auto alloc = [&](size_t bytes) -> void* {
        off = (off + 255) & ~(size_t)255;
        void* p = ws + off;
        off += bytes;
        return p;
    };

    int2*  rng    = (int2*) alloc(N_NODES * sizeof(int2));
    int*   btail  = (int*)  alloc(NBUK * sizeof(int));
    int*   ebuf   = (int*)  alloc((size_t)NBUK * BSTRIDE * sizeof(int));
    int*   col    = (int*)  alloc((size_t)NBUK * BSTRIDE * sizeof(int));
    float* dis    = (float*)alloc(N_NODES * sizeof(float));
    _Float16* Ga  = (_Float16*)alloc((size_t)N_NODES * D * sizeof(_Float16));
    _Float16* Gb  = (_Float16*)alloc((size_t)N_NODES * D * sizeof(_Float16));
    _Float16* H   = (_Float16*)alloc((size_t)N_NODES * D * sizeof(_Float16));

    const int nbPart = cdiv(N_EDGES, PART_TILE);   // 196

    k_binit<<<cdiv(NBUK, 256), 256, 0, stream>>>(btail);
    k_part<<<nbPart, 256, 0, stream>>>(src, dst, btail, ebuf);
    k_build<<<NBUK, 256, 0, stream>>>(ebuf, btail, rng, dis, col);

    const int nbGemm = cdiv(N_NODES, 64);    // 782
    const int nbAgg  = cdiv(N_NODES, 16);    // 3125

    // layer 0 transform: x (f32) @ W0 -> Ga
    k_gemm_scale<<<nbGemm, 256, 0, stream>>>(x, W0, dis, Ga);
    // agg layer 0 + fused W1 gemm -> Gb
    k_agg_fused<false><<<nbAgg, 256, 0, stream>>>(Ga, rng, col, dis, b0, W1, Gb);
    // agg layer 1 + fused W2 gemm -> Ga
    k_agg_fused<false><<<nbAgg, 256, 0, stream>>>(Gb, rng, col, dis, b1, W2, Ga);
    // agg layer 2 (final) -> H
    k_agg_fused<true><<<nbAgg, 256, 0, stream>>>(Ga, rng, col, dis, b2, nullptr, H);

    k_poolmlp<<<N_GRAPHS, 128, 0, stream>>>(H, batch, l1w, l1b, l2w, l2b,
                                            fcw, fcb, (float*)d_out);
}